// Round 3
// baseline (1398.241 us; speedup 1.0000x reference)
//
#include <hip/hip_runtime.h>
#include <stdint.h>

#define NDIM 16384
#define CAND_C 12
#define NCHUNK 32

typedef float  fvec4  __attribute__((ext_vector_type(4)));
typedef float  f32x4  __attribute__((ext_vector_type(4)));
typedef __bf16 bf16x8 __attribute__((ext_vector_type(8)));
typedef unsigned short u16x8 __attribute__((ext_vector_type(8)));
typedef unsigned short u16x4 __attribute__((ext_vector_type(4)));
typedef int    iv2    __attribute__((ext_vector_type(2)));

static_assert(sizeof(bf16x8) == 16, "bf16x8 must be 16B");
static_assert(sizeof(u16x8) == 16, "u16x8 must be 16B");

// ---------- helpers ----------

__device__ __forceinline__ unsigned short bf16r(float x) {
  unsigned u = __builtin_bit_cast(unsigned, x);
  return (unsigned short)((u + 0x7FFFu + ((u >> 16) & 1u)) >> 16);
}

__device__ __forceinline__ void split2(float v, unsigned short& h, unsigned short& l) {
  h = bf16r(v);
  float hf = __builtin_bit_cast(float, (unsigned)h << 16);
  l = bf16r(v - hf);
}

// global -> LDS direct copy, 16B per lane (linear dest per wave)
__device__ __forceinline__ void gload_lds16(const void* g, void* l) {
  typedef __attribute__((address_space(1))) const unsigned int gas_u32;
  typedef __attribute__((address_space(3))) unsigned int las_u32;
  __builtin_amdgcn_global_load_lds((gas_u32*)(uintptr_t)g,
                                   (las_u32*)(unsigned)(uintptr_t)l, 16, 0, 0);
}

#define MEMFENCE asm volatile("" ::: "memory")
#define BARRIER  do { MEMFENCE; __builtin_amdgcn_s_barrier(); MEMFENCE; } while (0)

// =====================================================================
// K1: fused linears: q->Bpack(swizzled split bf16), k->Apack(split bf16),
//     Am = x@Wm1a^T, Bm = x@Wm1b^T + bm1, XU = x@Wu1a^T + bu1
// =====================================================================
__global__ __launch_bounds__(256, 1) void k1_linears(
    const float* __restrict__ x,
    const float* __restrict__ Wq, const float* __restrict__ bq,
    const float* __restrict__ Wk, const float* __restrict__ bk,
    const float* __restrict__ Wm1, const float* __restrict__ bm1,
    const float* __restrict__ Wu1, const float* __restrict__ bu1,
    unsigned short* __restrict__ Apack, unsigned short* __restrict__ Bpack,
    float* __restrict__ Am, float* __restrict__ Bm, float* __restrict__ XU)
{
  extern __shared__ char lds[];
  float* xs = (float*)lds;              // 32768 B, [64][128] quad-swizzled
  float* wT = (float*)(lds + 32768);    // 65536 B, [c][co]

  const int t = threadIdx.x;
  const int rbase = blockIdx.x * 64;
  const int tr = t >> 4, tc = t & 15;

#pragma unroll
  for (int i = 0; i < 8; ++i) {
    int flat = (i * 256 + t) * 4;
    int row = flat >> 7, c = flat & 127;
    fvec4 v = *(const fvec4*)(x + (size_t)(rbase + row) * 128 + c);
    int q = (c >> 2) ^ ((row >> 2) & 7);
    *(fvec4*)(xs + row * 128 + q * 4) = v;
  }

  for (int s = 0; s < 5; ++s) {
    const float* W; int wstride, coff; const float* bias;
    if (s == 0)      { W = Wq;  wstride = 128; coff = 0;   bias = bq; }
    else if (s == 1) { W = Wk;  wstride = 128; coff = 0;   bias = bk; }
    else if (s == 2) { W = Wm1; wstride = 256; coff = 0;   bias = nullptr; }
    else if (s == 3) { W = Wm1; wstride = 256; coff = 128; bias = bm1; }
    else             { W = Wu1; wstride = 256; coff = 0;   bias = bu1; }

    __syncthreads();
    {
      int co = t >> 1, c0 = (t & 1) * 64;
      const float* wr = W + (size_t)co * wstride + coff + c0;
#pragma unroll
      for (int i = 0; i < 16; ++i) {
        fvec4 v = *(const fvec4*)(wr + 4 * i);
        wT[(c0 + 4 * i + 0) * 128 + co] = v[0];
        wT[(c0 + 4 * i + 1) * 128 + co] = v[1];
        wT[(c0 + 4 * i + 2) * 128 + co] = v[2];
        wT[(c0 + 4 * i + 3) * 128 + co] = v[3];
      }
    }
    __syncthreads();

    float acc[4][8];
#pragma unroll
    for (int rr = 0; rr < 4; ++rr)
#pragma unroll
      for (int i = 0; i < 8; ++i) acc[rr][i] = 0.f;

    for (int cq = 0; cq < 32; ++cq) {
      fvec4 xv[4];
#pragma unroll
      for (int rr = 0; rr < 4; ++rr)
        xv[rr] = *(const fvec4*)(xs + (tr * 4 + rr) * 128 + ((cq ^ (tr & 7)) << 2));
#pragma unroll
      for (int j = 0; j < 4; ++j) {
        int c = cq * 4 + j;
        fvec4 wa = *(const fvec4*)(wT + c * 128 + tc * 4);
        fvec4 wb = *(const fvec4*)(wT + c * 128 + 64 + tc * 4);
#pragma unroll
        for (int rr = 0; rr < 4; ++rr) {
          float xj = xv[rr][j];
#pragma unroll
          for (int i = 0; i < 4; ++i) {
            acc[rr][i]     += xj * wa[i];
            acc[rr][4 + i] += xj * wb[i];
          }
        }
      }
    }

    float ba[4] = {0, 0, 0, 0}, bb[4] = {0, 0, 0, 0};
    if (bias) {
      fvec4 t0 = *(const fvec4*)(bias + tc * 4);
      fvec4 t1 = *(const fvec4*)(bias + 64 + tc * 4);
#pragma unroll
      for (int i = 0; i < 4; ++i) { ba[i] = t0[i]; bb[i] = t1[i]; }
    }

#pragma unroll
    for (int rr = 0; rr < 4; ++rr) {
      int row = rbase + tr * 4 + rr;
      float v0[4], v1[4];
#pragma unroll
      for (int i = 0; i < 4; ++i) {
        v0[i] = acc[rr][i] + ba[i];
        v1[i] = acc[rr][4 + i] + bb[i];
      }
      if (s >= 2) {
        float* dst = (s == 2 ? Am : (s == 3 ? Bm : XU)) + (size_t)row * 128;
        fvec4 w0 = {v0[0], v0[1], v0[2], v0[3]};
        fvec4 w1 = {v1[0], v1[1], v1[2], v1[3]};
        *(fvec4*)(dst + tc * 4) = w0;
        *(fvec4*)(dst + 64 + tc * 4) = w1;
      } else {
        unsigned short h0[4], l0[4], h1[4], l1[4];
#pragma unroll
        for (int i = 0; i < 4; ++i) { split2(v0[i], h0[i], l0[i]); split2(v1[i], h1[i], l1[i]); }
        u16x4 H0 = {h0[0], h0[1], h0[2], h0[3]};
        u16x4 H1 = {h1[0], h1[1], h1[2], h1[3]};
        u16x4 L0 = {l0[0], l0[1], l0[2], l0[3]};
        u16x4 L1 = {l1[0], l1[1], l1[2], l1[3]};
        if (s == 1) {
          unsigned short* dst = Apack + (size_t)row * 256;
          *(u16x4*)(dst + tc * 4) = H0;
          *(u16x4*)(dst + 64 + tc * 4) = H1;
          *(u16x4*)(dst + 128 + tc * 4) = L0;
          *(u16x4*)(dst + 192 + tc * 4) = L1;
        } else {
          int jm = row & 7;
          int p0 = (((tc >> 1) ^ jm) << 3) | ((tc & 1) << 2);
          int p1 = (((8 + (tc >> 1)) ^ jm) << 3) | ((tc & 1) << 2);
          unsigned short* dst = Bpack + (size_t)row * 256;
          *(u16x4*)(dst + p0) = H0;
          *(u16x4*)(dst + p1) = H1;
          *(u16x4*)(dst + 128 + p0) = L0;
          *(u16x4*)(dst + 128 + p1) = L1;
        }
      }
    }
  }
}

// =====================================================================
// K2: fused split-bf16 GEMM + streaming top-20, swapped operands.
// grid 512 = 128 row-tiles x 4 j-quarters; 2 blocks/CU.
// 4 waves (2 wjj x 2 wii), wave tile [j 64][i 64], acc = D[j][i].
// Lane holds 16 sim values per owned row -> in-register candidate filter,
// rare survivors via LDS slot-atomics to per-row cand buffer.
// LDS: buf0(qh) 32K | buf1(ql) 32K | thr[128] | cnt[128] | over | cand[128][12] (8B)
// =====================================================================
__global__ __launch_bounds__(256, 2) void k2_simtopk(
    const unsigned short* __restrict__ Apack, const unsigned short* __restrict__ Bpack,
    float* __restrict__ plv, int* __restrict__ pli)
{
  extern __shared__ char lds[];
  float* thr  = (float*)(lds + 65536);
  int*   cnt  = (int*)(lds + 66048);
  int*   overp = (int*)(lds + 66560);
  iv2*   cand = (iv2*)(lds + 66576);   // [128][CAND_C], 8B entries

  const int t = threadIdx.x;
  const int lane = t & 63, wid = t >> 6;
  const int wii = wid >> 1, wjj = wid & 1;
  const int tile = blockIdx.x >> 2, jq = blockIdx.x & 3;
  const int rbase = tile * 128;
  const int jstart = jq * 4096;
  const int l15 = lane & 15, kg = lane >> 4;

  if (t < 128) { thr[t] = -3.0e38f; cnt[t] = 0; }
  if (t == 0) *overp = 0;

  // ---- i-side (k-vector) fragments in registers: hi and lo ----
  u16x8 kh[4][4], kl[4][4];
#pragma unroll
  for (int ii = 0; ii < 4; ++ii) {
    const unsigned short* arow = Apack + (size_t)(rbase + wii * 64 + ii * 16 + l15) * 256;
#pragma unroll
    for (int ks = 0; ks < 4; ++ks) {
      kh[ii][ks] = *(const u16x8*)(arow + ks * 32 + kg * 8);
      kl[ii][ks] = *(const u16x8*)(arow + 128 + ks * 32 + kg * 8);
    }
  }

  // ---- top-20 list: owner = lane<32; owner row = lane*4 + wid ----
  const int orow = lane * 4 + wid;
  float lv[20]; int li[20];
#pragma unroll
  for (int s = 0; s < 20; ++s) { lv[s] = -3.0e38f; li[s] = 0; }

  // ---- per-lane LDS byte offsets for q-side frags (XOR swizzle) ----
  int loff[4];
  {
    int lb = wjj * 16384 + l15 * 256;
#pragma unroll
    for (int ksl = 0; ksl < 4; ++ksl)
      loff[ksl] = lb + ((ksl * 64 + kg * 16) ^ ((l15 & 7) << 4));
  }

  auto stage = [&](int S) {   // S = chunk*2 + (0:q-hi -> buf0, 1:q-lo -> buf1)
    int ch = S >> 1; if (ch >= NCHUNK) ch -= NCHUNK;   // tail wrap: dummy re-stage keeps vmcnt math
    int soff = (S & 1) ? 256 : 0;
    int jb = jstart + ch * 128;
    char* base = lds + (S & 1) * 32768;
#pragma unroll
    for (int i = 0; i < 8; ++i) {
      int L = (i * 256 + t) * 16;
      int row = L >> 8, bir = L & 255;
      gload_lds16((const char*)Bpack + (size_t)(jb + row) * 512 + soff + bir, base + L);
    }
  };

  f32x4 acc[4][4];   // [jj][ii] = D[j][i]

  auto phase = [&](int bufbase, const u16x8 (&K)[4][4]) {
#pragma unroll
    for (int ksl = 0; ksl < 4; ++ksl) {
      bf16x8 q[4];
#pragma unroll
      for (int jj = 0; jj < 4; ++jj)
        q[jj] = __builtin_bit_cast(bf16x8, *(const u16x8*)(lds + bufbase + jj * 4096 + loff[ksl]));
#pragma unroll
      for (int jj = 0; jj < 4; ++jj)
#pragma unroll
        for (int ii = 0; ii < 4; ++ii)
          acc[jj][ii] = __builtin_amdgcn_mfma_f32_16x16x32_bf16(
              q[jj], __builtin_bit_cast(bf16x8, K[ii][ksl]), acc[jj][ii], 0, 0, 0);
    }
  };

  auto insert = [&](float v, int j) {
    float cv = v; int ci = j;
#pragma unroll
    for (int s = 0; s < 20; ++s) {
      bool m = cv > lv[s];
      float tv = lv[s]; int ti = li[s];
      lv[s] = m ? cv : tv; li[s] = m ? ci : ti;
      cv = m ? tv : cv;   ci = m ? ti : ci;
    }
  };

  unsigned msk[4];

  auto buildmask = [&]() {
#pragma unroll
    for (int ii = 0; ii < 4; ++ii) {
      float tv = thr[wii * 64 + ii * 16 + l15];
      unsigned m = 0;
#pragma unroll
      for (int jj = 0; jj < 4; ++jj) {
        f32x4 f = acc[jj][ii];
#pragma unroll
        for (int r = 0; r < 4; ++r)
          m |= (f[r] > tv) ? (1u << (jj * 4 + r)) : 0u;
      }
      msk[ii] = m;
    }
  };

  auto refilter = [&]() {
#pragma unroll
    for (int ii = 0; ii < 4; ++ii) {
      if (!msk[ii]) continue;
      float tv = thr[wii * 64 + ii * 16 + l15];
      unsigned m = 0;
#pragma unroll
      for (int jj = 0; jj < 4; ++jj) {
        f32x4 f = acc[jj][ii];
#pragma unroll
        for (int r = 0; r < 4; ++r)
          m |= (f[r] > tv) ? (1u << (jj * 4 + r)) : 0u;
      }
      msk[ii] &= m;
    }
  };

  auto drain = [&](int chunk) {
#pragma unroll
    for (int ii = 0; ii < 4; ++ii) {
      unsigned m = msk[ii];
      if (!m) continue;
      int row = wii * 64 + ii * 16 + l15;
      while (m) {
        int b = __builtin_ctz(m);
        int jj = b >> 2, r = b & 3;
        f32x4 f;
        switch (jj) {
          case 0: f = acc[0][ii]; break;
          case 1: f = acc[1][ii]; break;
          case 2: f = acc[2][ii]; break;
          default: f = acc[3][ii]; break;
        }
        float v = (r < 2) ? (r == 0 ? f[0] : f[1]) : (r == 2 ? f[2] : f[3]);
        int pos = atomicAdd(&cnt[row], 1);
        if (pos >= CAND_C) { *overp = 1; break; }   // keep bit; retry next round
        int jg = jstart + chunk * 128 + wjj * 64 + jj * 16 + kg * 4 + r;
        iv2 e; e[0] = (int)__builtin_bit_cast(unsigned, v); e[1] = jg;
        cand[row * CAND_C + pos] = e;
        m &= m - 1;
      }
      msk[ii] = m;
    }
  };

  auto ownerproc = [&]() {
    if (lane < 32) {
      int n = cnt[orow]; n = n > CAND_C ? CAND_C : n;
      for (int s = 0; s < n; ++s) {
        iv2 e = cand[orow * CAND_C + s];
        float v = __builtin_bit_cast(float, (unsigned)e[0]);
        if (v > lv[19]) insert(v, e[1]);
      }
      cnt[orow] = 0;
      thr[orow] = lv[19];
    }
  };

  // prologue: both slices of chunk 0 in flight
  stage(0);
  stage(1);

  for (int chunk = 0; chunk < NCHUNK; ++chunk) {
    asm volatile("s_waitcnt vmcnt(8)" ::: "memory");  // q-hi(chunk) landed (q-lo outstanding)
    BARRIER;                                          // (a)
#pragma unroll
    for (int jj = 0; jj < 4; ++jj)
#pragma unroll
      for (int ii = 0; ii < 4; ++ii) acc[jj][ii] = (f32x4){0.f, 0.f, 0.f, 0.f};

    phase(0, kh);        // qh . kh
    phase(0, kl);        // qh . kl
    BARRIER;                                          // (b) buf0 reads done
    stage(2 * chunk + 2);                             // q-hi(chunk+1) -> buf0
    asm volatile("s_waitcnt vmcnt(8)" ::: "memory");  // q-lo(chunk) landed
    BARRIER;                                          // (c)
    phase(32768, kh);    // ql . kh

    buildmask();
    drain(chunk);
    asm volatile("s_waitcnt lgkmcnt(0)" ::: "memory");
    BARRIER;                                          // (d) buf1 reads done + cand visible
    stage(2 * chunk + 3);                             // q-lo(chunk+1) -> buf1

    int af = *overp;
    ownerproc();
    while (af) {                                      // rare: capacity overflow rounds
      BARRIER;                                        // all read af; owner resets visible
      if (t == 0) *overp = 0;
      BARRIER;
      refilter();
      drain(chunk);
      asm volatile("s_waitcnt lgkmcnt(0)" ::: "memory");
      BARRIER;
      af = *overp;
      ownerproc();
    }
  }
  asm volatile("s_waitcnt vmcnt(0)" ::: "memory");    // drain tail dummy stages

  if (lane < 32) {
    int row = rbase + orow;
    float* pv = plv + ((size_t)jq * NDIM + row) * 20;
    int* pi = pli + ((size_t)jq * NDIM + row) * 20;
#pragma unroll
    for (int s = 0; s < 20; ++s) { pv[s] = lv[s]; pi[s] = li[s]; }
  }
}

// =====================================================================
// K2b: merge 4 sorted partial top-20 lists per row + softmax
// =====================================================================
__global__ __launch_bounds__(256) void k2b_merge(
    const float* __restrict__ plv, const int* __restrict__ pli,
    float* __restrict__ score, int* __restrict__ idx)
{
  int r = blockIdx.x * 256 + threadIdx.x;
  float hv[4]; int hj[4]; int p[4];
#pragma unroll
  for (int q = 0; q < 4; ++q) {
    p[q] = 0;
    hv[q] = plv[((size_t)q * NDIM + r) * 20];
    hj[q] = pli[((size_t)q * NDIM + r) * 20];
  }
  float vmax = fmaxf(fmaxf(hv[0], hv[1]), fmaxf(hv[2], hv[3]));
  float* sc = score + (size_t)r * 20;
  int* ix = idx + (size_t)r * 20;
  float sum = 0.f;
  for (int s = 0; s < 20; ++s) {
    int q = 0; float best = hv[0];
    if (hv[1] > best) { best = hv[1]; q = 1; }
    if (hv[2] > best) { best = hv[2]; q = 2; }
    if (hv[3] > best) { best = hv[3]; q = 3; }
    float e = expf(best - vmax);
    sum += e;
    sc[s] = e; ix[s] = hj[q];
    int np = p[q] + 1; p[q] = np;
    bool ok = np < 20;
    size_t base = ((size_t)q * NDIM + r) * 20;
    hv[q] = ok ? plv[base + np] : -3.0e38f;
    hj[q] = ok ? pli[base + np] : 0;
  }
  float inv = 1.0f / sum;
  for (int s = 0; s < 20; ++s) sc[s] *= inv;
}

// =====================================================================
// K3a: R[i] = sum_k score_k * relu(Am_i + Bm_{j_k})
// =====================================================================
__global__ __launch_bounds__(256) void k3a_gather(
    const float* __restrict__ Am, const float* __restrict__ Bm,
    const float* __restrict__ score, const int* __restrict__ idx,
    float* __restrict__ R)
{
  int t = threadIdx.x;
  int node = blockIdx.x * 32 + (t >> 3);
  int c0 = (t & 7) * 16;
  const float* am = Am + (size_t)node * 128 + c0;
  fvec4 a[4], r[4];
#pragma unroll
  for (int i = 0; i < 4; ++i) {
    a[i] = *(const fvec4*)(am + 4 * i);
    r[i] = (fvec4){0.f, 0.f, 0.f, 0.f};
  }
  const float* sc = score + (size_t)node * 20;
  const int* ix = idx + (size_t)node * 20;
  for (int k = 0; k < 20; ++k) {
    int j = ix[k]; float s = sc[k];
    const float* bm = Bm + (size_t)j * 128 + c0;
#pragma unroll
    for (int i = 0; i < 4; ++i) {
      fvec4 b = *(const fvec4*)(bm + 4 * i);
#pragma unroll
      for (int q = 0; q < 4; ++q)
        r[i][q] += s * fmaxf(a[i][q] + b[q], 0.f);
    }
  }
  float* outp = R + (size_t)node * 128 + c0;
#pragma unroll
  for (int i = 0; i < 4; ++i) *(fvec4*)(outp + 4 * i) = r[i];
}

// =====================================================================
// K3b: out = x + relu(XU + (R@Wm2^T + bm2)@Wu1b^T)@Wu2^T + bu2
// =====================================================================
__global__ __launch_bounds__(256, 1) void k3b_update(
    const float* __restrict__ R, const float* __restrict__ XU, const float* __restrict__ x,
    const float* __restrict__ Wm2, const float* __restrict__ bm2,
    const float* __restrict__ Wu1, const float* __restrict__ Wu2, const float* __restrict__ bu2,
    float* __restrict__ outg)
{
  extern __shared__ char lds[];
  float* in0 = (float*)lds;             // 32768
  float* in1 = (float*)(lds + 32768);   // 32768
  float* wT  = (float*)(lds + 65536);   // 65536

  const int t = threadIdx.x;
  const int rbase = blockIdx.x * 64;
  const int tr = t >> 4, tc = t & 15;

#pragma unroll
  for (int i = 0; i < 8; ++i) {
    int flat = (i * 256 + t) * 4;
    int row = flat >> 7, c = flat & 127;
    fvec4 v = *(const fvec4*)(R + (size_t)(rbase + row) * 128 + c);
    *(fvec4*)(in0 + row * 128 + (((c >> 2) ^ ((row >> 2) & 7)) << 2)) = v;
  }

  for (int s = 0; s < 3; ++s) {
    const float* W; int wstride, coff;
    if (s == 0)      { W = Wm2; wstride = 128; coff = 0; }
    else if (s == 1) { W = Wu1; wstride = 256; coff = 128; }
    else             { W = Wu2; wstride = 128; coff = 0; }

    __syncthreads();
    {
      int co = t >> 1, c0 = (t & 1) * 64;
      const float* wr = W + (size_t)co * wstride + coff + c0;
#pragma unroll
      for (int i = 0; i < 16; ++i) {
        fvec4 v = *(const fvec4*)(wr + 4 * i);
        wT[(c0 + 4 * i + 0) * 128 + co] = v[0];
        wT[(c0 + 4 * i + 1) * 128 + co] = v[1];
        wT[(c0 + 4 * i + 2) * 128 + co] = v[2];
        wT[(c0 + 4 * i + 3) * 128 + co] = v[3];
      }
    }
    __syncthreads();

    const float* in = (s == 1) ? in1 : in0;
    float acc[4][8];
#pragma unroll
    for (int rr = 0; rr < 4; ++rr)
#pragma unroll
      for (int i = 0; i < 8; ++i) acc[rr][i] = 0.f;

    for (int cq = 0; cq < 32; ++cq) {
      fvec4 xv[4];
#pragma unroll
      for (int rr = 0; rr < 4; ++rr)
        xv[rr] = *(const fvec4*)(in + (tr * 4 + rr) * 128 + ((cq ^ (tr & 7)) << 2));
#pragma unroll
      for (int j = 0; j < 4; ++j) {
        int c = cq * 4 + j;
        fvec4 wa = *(const fvec4*)(wT + c * 128 + tc * 4);
        fvec4 wb = *(const fvec4*)(wT + c * 128 + 64 + tc * 4);
#pragma unroll
        for (int rr = 0; rr < 4; ++rr) {
          float xj = xv[rr][j];
#pragma unroll
          for (int i = 0; i < 4; ++i) {
            acc[rr][i]     += xj * wa[i];
            acc[rr][4 + i] += xj * wb[i];
          }
        }
      }
    }

#pragma unroll
    for (int rr = 0; rr < 4; ++rr) {
      int row = rbase + tr * 4 + rr;
      int lrow = tr * 4 + rr;
      int q0 = tc ^ (tr & 7);
      int q1 = (16 + tc) ^ (tr & 7);
      if (s == 0) {
        fvec4 b0 = *(const fvec4*)(bm2 + tc * 4);
        fvec4 b1 = *(const fvec4*)(bm2 + 64 + tc * 4);
        fvec4 w0, w1;
#pragma unroll
        for (int i = 0; i < 4; ++i) { w0[i] = acc[rr][i] + b0[i]; w1[i] = acc[rr][4 + i] + b1[i]; }
        *(fvec4*)(in1 + lrow * 128 + q0 * 4) = w0;
        *(fvec4*)(in1 + lrow * 128 + q1 * 4) = w1;
      } else if (s == 1) {
        fvec4 x0 = *(const fvec4*)(XU + (size_t)row * 128 + tc * 4);
        fvec4 x1 = *(const fvec4*)(XU + (size_t)row * 128 + 64 + tc * 4);
        fvec4 w0, w1;
#pragma unroll
        for (int i = 0; i < 4; ++i) {
          w0[i] = fmaxf(acc[rr][i] + x0[i], 0.f);
          w1[i] = fmaxf(acc[rr][4 + i] + x1[i], 0.f);
        }
        *(fvec4*)(in0 + lrow * 128 + q0 * 4) = w0;
        *(fvec4*)(in0 + lrow * 128 + q1 * 4) = w1;
      } else {
        fvec4 b0 = *(const fvec4*)(bu2 + tc * 4);
        fvec4 b1 = *(const fvec4*)(bu2 + 64 + tc * 4);
        fvec4 x0 = *(const fvec4*)(x + (size_t)row * 128 + tc * 4);
        fvec4 x1 = *(const fvec4*)(x + (size_t)row * 128 + 64 + tc * 4);
        fvec4 w0, w1;
#pragma unroll
        for (int i = 0; i < 4; ++i) {
          w0[i] = x0[i] + acc[rr][i] + b0[i];
          w1[i] = x1[i] + acc[rr][4 + i] + b1[i];
        }
        *(fvec4*)(outg + (size_t)row * 128 + tc * 4) = w0;
        *(fvec4*)(outg + (size_t)row * 128 + 64 + tc * 4) = w1;
      }
    }
    __syncthreads();
  }
}

// =====================================================================
// launch
// =====================================================================
extern "C" void kernel_launch(void* const* d_in, const int* in_sizes, int n_in,
                              void* d_out, int out_size, void* d_ws, size_t ws_size,
                              hipStream_t stream) {
  const float* x   = (const float*)d_in[0];
  const float* Wq  = (const float*)d_in[1];
  const float* bq  = (const float*)d_in[2];
  const float* Wk  = (const float*)d_in[3];
  const float* bk  = (const float*)d_in[4];
  const float* Wm1 = (const float*)d_in[5];
  const float* bm1 = (const float*)d_in[6];
  const float* Wm2 = (const float*)d_in[7];
  const float* bm2 = (const float*)d_in[8];
  const float* Wu1 = (const float*)d_in[9];
  const float* bu1 = (const float*)d_in[10];
  const float* Wu2 = (const float*)d_in[11];
  const float* bu2 = (const float*)d_in[12];
  float* outp = (float*)d_out;

  const size_t NN = NDIM;
  char* w = (char*)d_ws;
  unsigned short* Apack = (unsigned short*)w; w += NN * 256 * 2;
  unsigned short* Bpack = (unsigned short*)w; w += NN * 256 * 2;
  float* Am = (float*)w; w += NN * 128 * 4;
  float* Bm = (float*)w; w += NN * 128 * 4;
  float* XU = (float*)w; w += NN * 128 * 4;
  char* w_plv = w;
  float* plv = (float*)w; w += 4 * NN * 20 * 4;
  int* pli = (int*)w; w += 4 * NN * 20 * 4;
  float* score = (float*)w; w += NN * 20 * 4;
  int* idxb = (int*)w; w += NN * 20 * 4;
  float* R = (float*)w_plv;   // overlays plv/pli (dead after k2b)

  hipFuncSetAttribute((const void*)k1_linears, hipFuncAttributeMaxDynamicSharedMemorySize, 98304);
  hipFuncSetAttribute((const void*)k2_simtopk, hipFuncAttributeMaxDynamicSharedMemorySize, 78912);
  hipFuncSetAttribute((const void*)k3b_update, hipFuncAttributeMaxDynamicSharedMemorySize, 131072);

  k1_linears<<<256, 256, 98304, stream>>>(x, Wq, bq, Wk, bk, Wm1, bm1, Wu1, bu1,
                                          Apack, Bpack, Am, Bm, XU);
  k2_simtopk<<<512, 256, 78912, stream>>>(Apack, Bpack, plv, pli);
  k2b_merge<<<64, 256, 0, stream>>>(plv, pli, score, idxb);
  k3a_gather<<<512, 256, 0, stream>>>(Am, Bm, score, idxb, R);
  k3b_update<<<256, 256, 131072, stream>>>(R, XU, x, Wm2, bm2, Wu1, Wu2, bu2, outp);
}

// Round 4
// 780.170 us; speedup vs baseline: 1.7922x; 1.7922x over previous
//
#include <hip/hip_runtime.h>
#include <stdint.h>

#define NDIM 16384
#define M_TOP 24
#define CAND_C 12
#define NCHUNK 32

typedef float  fvec4  __attribute__((ext_vector_type(4)));
typedef float  f32x4  __attribute__((ext_vector_type(4)));
typedef __bf16 bf16x8 __attribute__((ext_vector_type(8)));
typedef unsigned short u16x8 __attribute__((ext_vector_type(8)));
typedef unsigned short u16x4 __attribute__((ext_vector_type(4)));
typedef int    iv2    __attribute__((ext_vector_type(2)));

static_assert(sizeof(bf16x8) == 16, "bf16x8 must be 16B");
static_assert(sizeof(u16x8) == 16, "u16x8 must be 16B");

// ---------- helpers ----------

__device__ __forceinline__ unsigned short bf16r(float x) {
  unsigned u = __builtin_bit_cast(unsigned, x);
  return (unsigned short)((u + 0x7FFFu + ((u >> 16) & 1u)) >> 16);
}

// global -> LDS direct copy, 16B per lane (linear dest per wave)
__device__ __forceinline__ void gload_lds16(const void* g, void* l) {
  typedef __attribute__((address_space(1))) const unsigned int gas_u32;
  typedef __attribute__((address_space(3))) unsigned int las_u32;
  __builtin_amdgcn_global_load_lds((gas_u32*)(uintptr_t)g,
                                   (las_u32*)(unsigned)(uintptr_t)l, 16, 0, 0);
}

#define MEMFENCE asm volatile("" ::: "memory")
#define BARRIER  do { MEMFENCE; __builtin_amdgcn_s_barrier(); MEMFENCE; } while (0)

// =====================================================================
// K1: fused linears: q->qf(fp32)+Bpack(hi bf16, swizzled), k->kf+Apack,
//     Am = x@Wm1a^T, Bm = x@Wm1b^T + bm1, XU = x@Wu1a^T + bu1
// =====================================================================
__global__ __launch_bounds__(256, 1) void k1_linears(
    const float* __restrict__ x,
    const float* __restrict__ Wq, const float* __restrict__ bq,
    const float* __restrict__ Wk, const float* __restrict__ bk,
    const float* __restrict__ Wm1, const float* __restrict__ bm1,
    const float* __restrict__ Wu1, const float* __restrict__ bu1,
    unsigned short* __restrict__ Apack, unsigned short* __restrict__ Bpack,
    float* __restrict__ qf, float* __restrict__ kf,
    float* __restrict__ Am, float* __restrict__ Bm, float* __restrict__ XU)
{
  extern __shared__ char lds[];
  float* xs = (float*)lds;              // 32768 B, [64][128] quad-swizzled
  float* wT = (float*)(lds + 32768);    // 65536 B, [c][co]

  const int t = threadIdx.x;
  const int rbase = blockIdx.x * 64;
  const int tr = t >> 4, tc = t & 15;

#pragma unroll
  for (int i = 0; i < 8; ++i) {
    int flat = (i * 256 + t) * 4;
    int row = flat >> 7, c = flat & 127;
    fvec4 v = *(const fvec4*)(x + (size_t)(rbase + row) * 128 + c);
    int q = (c >> 2) ^ ((row >> 2) & 7);
    *(fvec4*)(xs + row * 128 + q * 4) = v;
  }

  for (int s = 0; s < 5; ++s) {
    const float* W; int wstride, coff; const float* bias;
    if (s == 0)      { W = Wq;  wstride = 128; coff = 0;   bias = bq; }
    else if (s == 1) { W = Wk;  wstride = 128; coff = 0;   bias = bk; }
    else if (s == 2) { W = Wm1; wstride = 256; coff = 0;   bias = nullptr; }
    else if (s == 3) { W = Wm1; wstride = 256; coff = 128; bias = bm1; }
    else             { W = Wu1; wstride = 256; coff = 0;   bias = bu1; }

    __syncthreads();
    {
      int co = t >> 1, c0 = (t & 1) * 64;
      const float* wr = W + (size_t)co * wstride + coff + c0;
#pragma unroll
      for (int i = 0; i < 16; ++i) {
        fvec4 v = *(const fvec4*)(wr + 4 * i);
        wT[(c0 + 4 * i + 0) * 128 + co] = v[0];
        wT[(c0 + 4 * i + 1) * 128 + co] = v[1];
        wT[(c0 + 4 * i + 2) * 128 + co] = v[2];
        wT[(c0 + 4 * i + 3) * 128 + co] = v[3];
      }
    }
    __syncthreads();

    float acc[4][8];
#pragma unroll
    for (int rr = 0; rr < 4; ++rr)
#pragma unroll
      for (int i = 0; i < 8; ++i) acc[rr][i] = 0.f;

    for (int cq = 0; cq < 32; ++cq) {
      fvec4 xv[4];
#pragma unroll
      for (int rr = 0; rr < 4; ++rr)
        xv[rr] = *(const fvec4*)(xs + (tr * 4 + rr) * 128 + ((cq ^ (tr & 7)) << 2));
#pragma unroll
      for (int j = 0; j < 4; ++j) {
        int c = cq * 4 + j;
        fvec4 wa = *(const fvec4*)(wT + c * 128 + tc * 4);
        fvec4 wb = *(const fvec4*)(wT + c * 128 + 64 + tc * 4);
#pragma unroll
        for (int rr = 0; rr < 4; ++rr) {
          float xj = xv[rr][j];
#pragma unroll
          for (int i = 0; i < 4; ++i) {
            acc[rr][i]     += xj * wa[i];
            acc[rr][4 + i] += xj * wb[i];
          }
        }
      }
    }

    float ba[4] = {0, 0, 0, 0}, bb[4] = {0, 0, 0, 0};
    if (bias) {
      fvec4 t0 = *(const fvec4*)(bias + tc * 4);
      fvec4 t1 = *(const fvec4*)(bias + 64 + tc * 4);
#pragma unroll
      for (int i = 0; i < 4; ++i) { ba[i] = t0[i]; bb[i] = t1[i]; }
    }

#pragma unroll
    for (int rr = 0; rr < 4; ++rr) {
      int row = rbase + tr * 4 + rr;
      float v0[4], v1[4];
#pragma unroll
      for (int i = 0; i < 4; ++i) {
        v0[i] = acc[rr][i] + ba[i];
        v1[i] = acc[rr][4 + i] + bb[i];
      }
      fvec4 w0 = {v0[0], v0[1], v0[2], v0[3]};
      fvec4 w1 = {v1[0], v1[1], v1[2], v1[3]};
      if (s >= 2) {
        float* dst = (s == 2 ? Am : (s == 3 ? Bm : XU)) + (size_t)row * 128;
        *(fvec4*)(dst + tc * 4) = w0;
        *(fvec4*)(dst + 64 + tc * 4) = w1;
      } else {
        float* fdst = (s == 0 ? qf : kf) + (size_t)row * 128;
        *(fvec4*)(fdst + tc * 4) = w0;
        *(fvec4*)(fdst + 64 + tc * 4) = w1;
        unsigned short h0[4], h1[4];
#pragma unroll
        for (int i = 0; i < 4; ++i) { h0[i] = bf16r(v0[i]); h1[i] = bf16r(v1[i]); }
        u16x4 H0 = {h0[0], h0[1], h0[2], h0[3]};
        u16x4 H1 = {h1[0], h1[1], h1[2], h1[3]};
        if (s == 1) {   // k -> Apack, plain hi layout (128 shorts/row)
          unsigned short* dst = Apack + (size_t)row * 128;
          *(u16x4*)(dst + tc * 4) = H0;
          *(u16x4*)(dst + 64 + tc * 4) = H1;
        } else {        // q -> Bpack, group-swizzled hi (128 shorts/row)
          int jm = row & 7;
          int p0 = (((tc >> 1) ^ jm) << 3) | ((tc & 1) << 2);
          int p1 = (((8 + (tc >> 1)) ^ jm) << 3) | ((tc & 1) << 2);
          unsigned short* dst = Bpack + (size_t)row * 128;
          *(u16x4*)(dst + p0) = H0;
          *(u16x4*)(dst + p1) = H1;
        }
      }
    }
  }
}

// =====================================================================
// K2: hi.hi bf16 GEMM (K=128) + streaming top-24 per row per j-quarter.
// grid 512 = 128 row-tiles x 4 j-quarters; 2 blocks/CU (no spills: ~215 regs).
// 4 waves (2 wii x 2 wjj), wave tile [j 64][i 64], acc = D[j][i].
// LDS: buf0 32K | buf1 32K | thr[128] | cnt[128] | over | cand[128][12]
// =====================================================================
__global__ __launch_bounds__(256, 2) void k2_simtopk(
    const unsigned short* __restrict__ Apack, const unsigned short* __restrict__ Bpack,
    float* __restrict__ plv, int* __restrict__ pli)
{
  extern __shared__ char lds[];
  float* thr   = (float*)(lds + 65536);
  int*   cnt   = (int*)(lds + 66048);
  int*   overp = (int*)(lds + 66560);
  iv2*   cand  = (iv2*)(lds + 66576);   // [128][CAND_C], 8B entries

  const int t = threadIdx.x;
  const int lane = t & 63, wid = t >> 6;
  const int wii = wid >> 1, wjj = wid & 1;
  const int tile = blockIdx.x >> 2, jq = blockIdx.x & 3;
  const int rbase = tile * 128;
  const int jstart = jq * 4096;
  const int l15 = lane & 15, kg = lane >> 4;

  if (t < 128) { thr[t] = -3.0e38f; cnt[t] = 0; }
  if (t == 0) *overp = 0;

  // ---- k-hi fragments (i-side, B operand) in registers ----
  u16x8 kh[4][4];
#pragma unroll
  for (int ii = 0; ii < 4; ++ii) {
    const unsigned short* arow = Apack + (size_t)(rbase + wii * 64 + ii * 16 + l15) * 128;
#pragma unroll
    for (int ks = 0; ks < 4; ++ks)
      kh[ii][ks] = *(const u16x8*)(arow + ks * 32 + kg * 8);
  }

  // ---- top-24 list: owner = lane<32; owner row = lane*4 + wid ----
  const int orow = lane * 4 + wid;
  float lv[M_TOP]; int li[M_TOP];
#pragma unroll
  for (int s = 0; s < M_TOP; ++s) { lv[s] = -3.0e38f; li[s] = 0; }

  // ---- per-lane LDS byte offsets for q-frags (XOR bank swizzle) ----
  int loff[4];
  {
    int lb = wjj * 16384 + l15 * 256;
#pragma unroll
    for (int ksl = 0; ksl < 4; ++ksl)
      loff[ksl] = lb + ((ksl * 64 + kg * 16) ^ ((l15 & 7) << 4));
  }

  auto stage = [&](int ch) {
    if (ch >= NCHUNK) ch -= NCHUNK;   // tail wrap: dummy re-stage keeps vmcnt math
    int jb = jstart + ch * 128;
    char* base = lds + (ch & 1) * 32768;
#pragma unroll
    for (int i = 0; i < 8; ++i) {
      int L = (i * 256 + t) * 16;
      int row = L >> 8, bir = L & 255;
      gload_lds16((const char*)Bpack + (size_t)(jb + row) * 256 + bir, base + L);
    }
  };

  f32x4 acc[4][4];   // [jj][ii] = D[j][i]

  auto insert = [&](float v, int j) {
    float cv = v; int ci = j;
#pragma unroll
    for (int s = 0; s < M_TOP; ++s) {
      bool m = cv > lv[s];
      float tv = lv[s]; int ti = li[s];
      lv[s] = m ? cv : tv; li[s] = m ? ci : ti;
      cv = m ? tv : cv;   ci = m ? ti : ci;
    }
  };

  unsigned msk[4];

  auto buildmask = [&]() {
#pragma unroll
    for (int ii = 0; ii < 4; ++ii) {
      float tv = thr[wii * 64 + ii * 16 + l15];
      unsigned m = 0;
#pragma unroll
      for (int jj = 0; jj < 4; ++jj) {
        f32x4 f = acc[jj][ii];
#pragma unroll
        for (int r = 0; r < 4; ++r)
          m |= (f[r] > tv) ? (1u << (jj * 4 + r)) : 0u;
      }
      msk[ii] = m;
    }
  };

  auto refilter = [&]() {
#pragma unroll
    for (int ii = 0; ii < 4; ++ii) {
      if (!msk[ii]) continue;
      float tv = thr[wii * 64 + ii * 16 + l15];
      unsigned m = 0;
#pragma unroll
      for (int jj = 0; jj < 4; ++jj) {
        f32x4 f = acc[jj][ii];
#pragma unroll
        for (int r = 0; r < 4; ++r)
          m |= (f[r] > tv) ? (1u << (jj * 4 + r)) : 0u;
      }
      msk[ii] &= m;
    }
  };

  auto drain = [&](int chunk) {
#pragma unroll
    for (int ii = 0; ii < 4; ++ii) {
      unsigned m = msk[ii];
      if (!m) continue;
      int row = wii * 64 + ii * 16 + l15;
      while (m) {
        int b = __builtin_ctz(m);
        int jj = b >> 2, r = b & 3;
        f32x4 f;
        switch (jj) {
          case 0: f = acc[0][ii]; break;
          case 1: f = acc[1][ii]; break;
          case 2: f = acc[2][ii]; break;
          default: f = acc[3][ii]; break;
        }
        float v = (r < 2) ? (r == 0 ? f[0] : f[1]) : (r == 2 ? f[2] : f[3]);
        int pos = atomicAdd(&cnt[row], 1);
        if (pos >= CAND_C) { *overp = 1; break; }   // keep bit; retry round
        int jg = jstart + chunk * 128 + wjj * 64 + jj * 16 + kg * 4 + r;
        iv2 e; e[0] = (int)__builtin_bit_cast(unsigned, v); e[1] = jg;
        cand[row * CAND_C + pos] = e;
        m &= m - 1;
      }
      msk[ii] = m;
    }
  };

  auto ownerproc = [&]() {
    if (lane < 32) {
      int n = cnt[orow]; n = n > CAND_C ? CAND_C : n;
      for (int s = 0; s < n; ++s) {
        iv2 e = cand[orow * CAND_C + s];
        float v = __builtin_bit_cast(float, (unsigned)e[0]);
        if (v > lv[M_TOP - 1]) insert(v, e[1]);
      }
      cnt[orow] = 0;
      thr[orow] = lv[M_TOP - 1];
    }
  };

  // prologue: two chunks in flight
  stage(0);
  stage(1);

  for (int chunk = 0; chunk < NCHUNK; ++chunk) {
    asm volatile("s_waitcnt vmcnt(8)" ::: "memory");  // chunk's buf landed (next outstanding)
    BARRIER;                                          // (a) buf ready block-wide
#pragma unroll
    for (int jj = 0; jj < 4; ++jj)
#pragma unroll
      for (int ii = 0; ii < 4; ++ii) acc[jj][ii] = (f32x4){0.f, 0.f, 0.f, 0.f};

    const char* buf = lds + (chunk & 1) * 32768;
#pragma unroll
    for (int ksl = 0; ksl < 4; ++ksl) {
      bf16x8 q[4];
#pragma unroll
      for (int jj = 0; jj < 4; ++jj)
        q[jj] = __builtin_bit_cast(bf16x8, *(const u16x8*)(buf + jj * 4096 + loff[ksl]));
#pragma unroll
      for (int jj = 0; jj < 4; ++jj)
#pragma unroll
        for (int ii = 0; ii < 4; ++ii)
          acc[jj][ii] = __builtin_amdgcn_mfma_f32_16x16x32_bf16(
              q[jj], __builtin_bit_cast(bf16x8, kh[ii][ksl]), acc[jj][ii], 0, 0, 0);
    }

    BARRIER;                                          // (b) buf reads done
    stage(chunk + 2);                                 // overwrite consumed buffer

    buildmask();
    drain(chunk);
    asm volatile("s_waitcnt lgkmcnt(0)" ::: "memory");
    BARRIER;                                          // (c) cand/over visible

    int af = *overp;
    ownerproc();
    while (af) {                                      // rare: capacity overflow rounds
      BARRIER;                                        // all read af; owner writes visible
      if (t == 0) *overp = 0;
      BARRIER;
      refilter();
      drain(chunk);
      asm volatile("s_waitcnt lgkmcnt(0)" ::: "memory");
      BARRIER;
      af = *overp;
      ownerproc();
    }
  }
  asm volatile("s_waitcnt vmcnt(0)" ::: "memory");    // drain tail dummy stages

  if (lane < 32) {
    int row = rbase + orow;
    float* pv = plv + ((size_t)jq * NDIM + row) * M_TOP;
    int* pi = pli + ((size_t)jq * NDIM + row) * M_TOP;
#pragma unroll
    for (int s = 0; s < M_TOP; ++s) { pv[s] = lv[s]; pi[s] = li[s]; }
  }
}

// =====================================================================
// K2c: merge 4x24 hi-lists -> top-24, rescore in exact fp32 (qf,kf),
//      select true top-20 + softmax. 64 rows per block.
// =====================================================================
__global__ __launch_bounds__(256) void k2c_rescore(
    const float* __restrict__ plv, const int* __restrict__ pli,
    const float* __restrict__ qf, const float* __restrict__ kf,
    float* __restrict__ score, int* __restrict__ idx)
{
  __shared__ int   midx[64][M_TOP];
  __shared__ float simv[64][M_TOP];
  const int t = threadIdx.x;
  const int rbase = blockIdx.x * 64;

  if (t < 64) {
    int r = rbase + t;
    float hv[4]; int hj[4]; int p[4];
#pragma unroll
    for (int q = 0; q < 4; ++q) {
      size_t base = ((size_t)q * NDIM + r) * M_TOP;
      hv[q] = plv[base]; hj[q] = pli[base]; p[q] = 0;
    }
    for (int s = 0; s < M_TOP; ++s) {
      int qb = 0; float best = hv[0];
      if (hv[1] > best) { best = hv[1]; qb = 1; }
      if (hv[2] > best) { best = hv[2]; qb = 2; }
      if (hv[3] > best) { best = hv[3]; qb = 3; }
      midx[t][s] = hj[qb];
      int np = p[qb] + 1; p[qb] = np;
      bool ok = np < M_TOP;
      size_t base = ((size_t)qb * NDIM + r) * M_TOP;
      hv[qb] = ok ? plv[base + np] : -3.0e38f;
      hj[qb] = ok ? pli[base + np] : 0;
    }
  }
  __syncthreads();
  {
    int r = t >> 2, g = t & 3;
    const float* krow = kf + (size_t)(rbase + r) * 128;
#pragma unroll
    for (int s = 0; s < 6; ++s) {
      int c = g * 6 + s;
      int j = midx[r][c];
      const float* qrow = qf + (size_t)j * 128;
      fvec4 a4 = {0.f, 0.f, 0.f, 0.f};
#pragma unroll
      for (int i = 0; i < 32; ++i) {
        fvec4 kv = *(const fvec4*)(krow + i * 4);
        fvec4 qv = *(const fvec4*)(qrow + i * 4);
        a4 += kv * qv;
      }
      simv[r][c] = a4[0] + a4[1] + a4[2] + a4[3];
    }
  }
  __syncthreads();
  if (t < 64) {
    float lv[20]; int li[20];
#pragma unroll
    for (int s = 0; s < 20; ++s) { lv[s] = -3.0e38f; li[s] = 0; }
    for (int c = 0; c < M_TOP; ++c) {
      float v = simv[t][c]; int j = midx[t][c];
      if (v > lv[19]) {
        float cv = v; int ci = j;
#pragma unroll
        for (int s = 0; s < 20; ++s) {
          bool m = cv > lv[s];
          float tv = lv[s]; int ti = li[s];
          lv[s] = m ? cv : tv; li[s] = m ? ci : ti;
          cv = m ? tv : cv;   ci = m ? ti : ci;
        }
      }
    }
    float vmax = lv[0], sum = 0.f;
    float e[20];
#pragma unroll
    for (int s = 0; s < 20; ++s) { e[s] = expf(lv[s] - vmax); sum += e[s]; }
    float inv = 1.0f / sum;
    float* sc = score + (size_t)(rbase + t) * 20;
    int* ix = idx + (size_t)(rbase + t) * 20;
#pragma unroll
    for (int s = 0; s < 20; ++s) { sc[s] = e[s] * inv; ix[s] = li[s]; }
  }
}

// =====================================================================
// K3a: R[i] = sum_k score_k * relu(Am_i + Bm_{j_k})
// =====================================================================
__global__ __launch_bounds__(256) void k3a_gather(
    const float* __restrict__ Am, const float* __restrict__ Bm,
    const float* __restrict__ score, const int* __restrict__ idx,
    float* __restrict__ R)
{
  int t = threadIdx.x;
  int node = blockIdx.x * 32 + (t >> 3);
  int c0 = (t & 7) * 16;
  const float* am = Am + (size_t)node * 128 + c0;
  fvec4 a[4], r[4];
#pragma unroll
  for (int i = 0; i < 4; ++i) {
    a[i] = *(const fvec4*)(am + 4 * i);
    r[i] = (fvec4){0.f, 0.f, 0.f, 0.f};
  }
  const float* sc = score + (size_t)node * 20;
  const int* ix = idx + (size_t)node * 20;
  for (int k = 0; k < 20; ++k) {
    int j = ix[k]; float s = sc[k];
    const float* bm = Bm + (size_t)j * 128 + c0;
#pragma unroll
    for (int i = 0; i < 4; ++i) {
      fvec4 b = *(const fvec4*)(bm + 4 * i);
#pragma unroll
      for (int q = 0; q < 4; ++q)
        r[i][q] += s * fmaxf(a[i][q] + b[q], 0.f);
    }
  }
  float* outp = R + (size_t)node * 128 + c0;
#pragma unroll
  for (int i = 0; i < 4; ++i) *(fvec4*)(outp + 4 * i) = r[i];
}

// =====================================================================
// K3b: out = x + relu(XU + (R@Wm2^T + bm2)@Wu1b^T)@Wu2^T + bu2
// =====================================================================
__global__ __launch_bounds__(256, 1) void k3b_update(
    const float* __restrict__ R, const float* __restrict__ XU, const float* __restrict__ x,
    const float* __restrict__ Wm2, const float* __restrict__ bm2,
    const float* __restrict__ Wu1, const float* __restrict__ Wu2, const float* __restrict__ bu2,
    float* __restrict__ outg)
{
  extern __shared__ char lds[];
  float* in0 = (float*)lds;             // 32768
  float* in1 = (float*)(lds + 32768);   // 32768
  float* wT  = (float*)(lds + 65536);   // 65536

  const int t = threadIdx.x;
  const int rbase = blockIdx.x * 64;
  const int tr = t >> 4, tc = t & 15;

#pragma unroll
  for (int i = 0; i < 8; ++i) {
    int flat = (i * 256 + t) * 4;
    int row = flat >> 7, c = flat & 127;
    fvec4 v = *(const fvec4*)(R + (size_t)(rbase + row) * 128 + c);
    *(fvec4*)(in0 + row * 128 + (((c >> 2) ^ ((row >> 2) & 7)) << 2)) = v;
  }

  for (int s = 0; s < 3; ++s) {
    const float* W; int wstride, coff;
    if (s == 0)      { W = Wm2; wstride = 128; coff = 0; }
    else if (s == 1) { W = Wu1; wstride = 256; coff = 128; }
    else             { W = Wu2; wstride = 128; coff = 0; }

    __syncthreads();
    {
      int co = t >> 1, c0 = (t & 1) * 64;
      const float* wr = W + (size_t)co * wstride + coff + c0;
#pragma unroll
      for (int i = 0; i < 16; ++i) {
        fvec4 v = *(const fvec4*)(wr + 4 * i);
        wT[(c0 + 4 * i + 0) * 128 + co] = v[0];
        wT[(c0 + 4 * i + 1) * 128 + co] = v[1];
        wT[(c0 + 4 * i + 2) * 128 + co] = v[2];
        wT[(c0 + 4 * i + 3) * 128 + co] = v[3];
      }
    }
    __syncthreads();

    const float* in = (s == 1) ? in1 : in0;
    float acc[4][8];
#pragma unroll
    for (int rr = 0; rr < 4; ++rr)
#pragma unroll
      for (int i = 0; i < 8; ++i) acc[rr][i] = 0.f;

    for (int cq = 0; cq < 32; ++cq) {
      fvec4 xv[4];
#pragma unroll
      for (int rr = 0; rr < 4; ++rr)
        xv[rr] = *(const fvec4*)(in + (tr * 4 + rr) * 128 + ((cq ^ (tr & 7)) << 2));
#pragma unroll
      for (int j = 0; j < 4; ++j) {
        int c = cq * 4 + j;
        fvec4 wa = *(const fvec4*)(wT + c * 128 + tc * 4);
        fvec4 wb = *(const fvec4*)(wT + c * 128 + 64 + tc * 4);
#pragma unroll
        for (int rr = 0; rr < 4; ++rr) {
          float xj = xv[rr][j];
#pragma unroll
          for (int i = 0; i < 4; ++i) {
            acc[rr][i]     += xj * wa[i];
            acc[rr][4 + i] += xj * wb[i];
          }
        }
      }
    }

#pragma unroll
    for (int rr = 0; rr < 4; ++rr) {
      int row = rbase + tr * 4 + rr;
      int lrow = tr * 4 + rr;
      int q0 = tc ^ (tr & 7);
      int q1 = (16 + tc) ^ (tr & 7);
      if (s == 0) {
        fvec4 b0 = *(const fvec4*)(bm2 + tc * 4);
        fvec4 b1 = *(const fvec4*)(bm2 + 64 + tc * 4);
        fvec4 w0, w1;
#pragma unroll
        for (int i = 0; i < 4; ++i) { w0[i] = acc[rr][i] + b0[i]; w1[i] = acc[rr][4 + i] + b1[i]; }
        *(fvec4*)(in1 + lrow * 128 + q0 * 4) = w0;
        *(fvec4*)(in1 + lrow * 128 + q1 * 4) = w1;
      } else if (s == 1) {
        fvec4 x0 = *(const fvec4*)(XU + (size_t)row * 128 + tc * 4);
        fvec4 x1 = *(const fvec4*)(XU + (size_t)row * 128 + 64 + tc * 4);
        fvec4 w0, w1;
#pragma unroll
        for (int i = 0; i < 4; ++i) {
          w0[i] = fmaxf(acc[rr][i] + x0[i], 0.f);
          w1[i] = fmaxf(acc[rr][4 + i] + x1[i], 0.f);
        }
        *(fvec4*)(in0 + lrow * 128 + q0 * 4) = w0;
        *(fvec4*)(in0 + lrow * 128 + q1 * 4) = w1;
      } else {
        fvec4 b0 = *(const fvec4*)(bu2 + tc * 4);
        fvec4 b1 = *(const fvec4*)(bu2 + 64 + tc * 4);
        fvec4 x0 = *(const fvec4*)(x + (size_t)row * 128 + tc * 4);
        fvec4 x1 = *(const fvec4*)(x + (size_t)row * 128 + 64 + tc * 4);
        fvec4 w0, w1;
#pragma unroll
        for (int i = 0; i < 4; ++i) {
          w0[i] = x0[i] + acc[rr][i] + b0[i];
          w1[i] = x1[i] + acc[rr][4 + i] + b1[i];
        }
        *(fvec4*)(outg + (size_t)row * 128 + tc * 4) = w0;
        *(fvec4*)(outg + (size_t)row * 128 + 64 + tc * 4) = w1;
      }
    }
    __syncthreads();
  }
}

// =====================================================================
// launch
// =====================================================================
extern "C" void kernel_launch(void* const* d_in, const int* in_sizes, int n_in,
                              void* d_out, int out_size, void* d_ws, size_t ws_size,
                              hipStream_t stream) {
  const float* x   = (const float*)d_in[0];
  const float* Wq  = (const float*)d_in[1];
  const float* bq  = (const float*)d_in[2];
  const float* Wk  = (const float*)d_in[3];
  const float* bk  = (const float*)d_in[4];
  const float* Wm1 = (const float*)d_in[5];
  const float* bm1 = (const float*)d_in[6];
  const float* Wm2 = (const float*)d_in[7];
  const float* bm2 = (const float*)d_in[8];
  const float* Wu1 = (const float*)d_in[9];
  const float* bu1 = (const float*)d_in[10];
  const float* Wu2 = (const float*)d_in[11];
  const float* bu2 = (const float*)d_in[12];
  float* outp = (float*)d_out;

  const size_t NN = NDIM;
  char* w = (char*)d_ws;
  unsigned short* Apack = (unsigned short*)w; w += NN * 128 * 2;
  unsigned short* Bpack = (unsigned short*)w; w += NN * 128 * 2;
  float* qf = (float*)w; w += NN * 128 * 4;
  float* kf = (float*)w; w += NN * 128 * 4;
  float* Am = (float*)w; w += NN * 128 * 4;
  float* Bm = (float*)w; w += NN * 128 * 4;
  float* XU = (float*)w; w += NN * 128 * 4;
  char* w_plv = w;
  float* plv = (float*)w; w += 4 * NN * M_TOP * 4;
  int* pli = (int*)w; w += 4 * NN * M_TOP * 4;
  float* score = (float*)w; w += NN * 20 * 4;
  int* idxb = (int*)w; w += NN * 20 * 4;
  float* R = (float*)w_plv;   // overlays plv/pli (dead after k2c)

  hipFuncSetAttribute((const void*)k1_linears, hipFuncAttributeMaxDynamicSharedMemorySize, 98304);
  hipFuncSetAttribute((const void*)k2_simtopk, hipFuncAttributeMaxDynamicSharedMemorySize, 78864);
  hipFuncSetAttribute((const void*)k3b_update, hipFuncAttributeMaxDynamicSharedMemorySize, 131072);

  k1_linears<<<256, 256, 98304, stream>>>(x, Wq, bq, Wk, bk, Wm1, bm1, Wu1, bu1,
                                          Apack, Bpack, qf, kf, Am, Bm, XU);
  k2_simtopk<<<512, 256, 78864, stream>>>(Apack, Bpack, plv, pli);
  k2c_rescore<<<256, 256, 0, stream>>>(plv, pli, qf, kf, score, idxb);
  k3a_gather<<<512, 256, 0, stream>>>(Am, Bm, score, idxb, R);
  k3b_update<<<256, 256, 131072, stream>>>(R, XU, x, Wm2, bm2, Wu1, Wu2, bu2, outp);
}